// Round 3
// baseline (622.687 us; speedup 1.0000x reference)
//
#include <hip/hip_runtime.h>

// Problem constants (shapes fixed by reference setup_inputs)
#define NS   64
#define DDIM 512
#define CDIM 512
#define TDIM 1024
#define CB   64     // c-rows per workgroup
#define TBLK 256    // t-tile per outer iteration (2 w-rows)
#define BK   64     // k(d)-chunk staged per inner iteration
#define SCALE 0.04419417382415922f   // 512^-0.5

typedef __attribute__((ext_vector_type(4)))  float f32x4;
typedef __attribute__((ext_vector_type(16))) float f32x16;
typedef __attribute__((ext_vector_type(4)))  short s16x4;
typedef __attribute__((ext_vector_type(8)))  short s16x8;

// LDS-only barrier: does NOT drain vmcnt, keeps global prefetches in flight.
#define LGKM_BARRIER() asm volatile("s_waitcnt lgkmcnt(0)\n\ts_barrier" ::: "memory")

__device__ __forceinline__ unsigned short f2bf(float f) {
  unsigned int b = __float_as_uint(f);
  return (unsigned short)((b + 0x7FFFu + ((b >> 16) & 1u)) >> 16);
}
__device__ __forceinline__ unsigned int pk2(float a, float b) {
  return (unsigned int)f2bf(a) | ((unsigned int)f2bf(b) << 16);
}

// LDS layout (bytes). Strides in shorts; 68 => 34 dw === 2 mod 32 (2-way, free
// for b64 frag reads AND for remapped staging writes).
#define AS_STRIDE 68     // 64 k + 4 pad
#define BS_STRIDE 68
#define PS_STRIDE 260    // 256 t + 4 pad (b64-aligned rows)
#define AS0_OFF 0        // 64*68*2  = 8704
#define AS1_OFF 8704
#define BS0_OFF 17408    // 256*68*2 = 34816
#define BS1_OFF 52224
#define PS_OFF  87040    // 64*260*2 = 33280
#define ZP_OFF  120320   // Zpart[4][64] f32 = 1024
#define IZ_OFF  121344   // invZ[64] f32
#define SMEM_BYTES 121600

struct Stage { f32x4 q0, q1, ka[4], kb[4]; };  // 40 VGPRs in flight
struct VRegs { f32x4 a0, a1, b0, b1; };

__device__ __forceinline__ void issue_v(VRegs& r, const float* __restrict__ vrow,
                                        int ks, int lhi) {
  const int kk = ks * 16 + 8 * lhi;
  r.a0 = *(const f32x4*)(vrow + kk);
  r.a1 = *(const f32x4*)(vrow + kk + 4);
  r.b0 = *(const f32x4*)(vrow + (size_t)32 * TDIM + kk);
  r.b1 = *(const f32x4*)(vrow + (size_t)32 * TDIM + kk + 4);
}

__device__ __forceinline__ s16x8 cvt_bv(const f32x4& x0, const f32x4& x1) {
  s16x8 bv;
  bv[0] = (short)f2bf(x0[0]); bv[1] = (short)f2bf(x0[1]);
  bv[2] = (short)f2bf(x0[2]); bv[3] = (short)f2bf(x0[3]);
  bv[4] = (short)f2bf(x1[0]); bv[5] = (short)f2bf(x1[1]);
  bv[6] = (short)f2bf(x1[2]); bv[7] = (short)f2bf(x1[3]);
  return bv;
}

__global__ __launch_bounds__(512, 2)
void attn_fused_kernel(const float* __restrict__ query,
                       const float* __restrict__ key,
                       const float* __restrict__ value,
                       const float* __restrict__ ratios,
                       float* __restrict__ out)
{
  __shared__ __align__(16) char smem[SMEM_BYTES];
  unsigned short* Asbuf[2] = {(unsigned short*)(smem + AS0_OFF),
                              (unsigned short*)(smem + AS1_OFF)};
  unsigned short* Bsbuf[2] = {(unsigned short*)(smem + BS0_OFF),
                              (unsigned short*)(smem + BS1_OFF)};
  unsigned short* Ps = (unsigned short*)(smem + PS_OFF);
  float* Zpart = (float*)(smem + ZP_OFF);
  float* invZ  = (float*)(smem + IZ_OFF);
  float* Obuf  = (float*)smem;   // epilogue transpose buffer (overlaps As/Bs)

  // XCD swizzle: all 8 c-blocks of one sample land on one XCD (shared L2).
  const int lin  = blockIdx.x + (int)gridDim.x * blockIdx.y;  // 0..511
  const int n    = 8 * (lin & 7) + (lin >> 6);
  const int c0   = ((lin >> 3) & 7) * CB;

  const int tid  = threadIdx.x;
  const int wave = tid >> 6;
  const int lane = tid & 63;
  const int l31  = lane & 31;
  const int lhi  = lane >> 5;

  float rr = ratios[n];
  int vw = (int)floorf(128.0f * rr + 0.5f);
  if (vw > 128) vw = 128;

  const float* qbase = query + (size_t)n * DDIM * CDIM + c0;
  const float* kbase = key   + (size_t)n * DDIM * TDIM;
  const float* vbase = value + (size_t)n * DDIM * TDIM;

  // staging maps (bank-spread: write-instr lanes hit 2-way max)
  const int kpq = (tid & 7) + 8 * (tid >> 7);  // Q k-pair 0..31
  const int cg  = (tid >> 3) & 15;             // Q c-group of 4
  const int kpk = tid & 7;                     // K k-pair base (+8i)
  const int tg  = tid >> 3;                    // K t-group of 4 (0..63)

  // phase-1 wave tiling: ct = c-tile (2), ttp = 64-wide t-strip (4)
  const int ct  = wave & 1;
  const int ttp = wave >> 1;

  f32x16 o_acc[2][2];
  #pragma unroll
  for (int a = 0; a < 2; ++a)
    #pragma unroll
    for (int b = 0; b < 2; ++b)
      #pragma unroll
      for (int i = 0; i < 16; ++i) o_acc[a][b][i] = 0.0f;

  float z_loc[16];
  #pragma unroll
  for (int i = 0; i < 16; ++i) z_loc[i] = 0.0f;

  // ---- pipeline helpers -------------------------------------------------
  Stage st;
  auto issue_stage = [&](int g) {
    const int k0 = (g & 7) * BK;
    const int t0 = (g >> 3) * TBLK;
    const float* gq = qbase + (size_t)(k0 + 2 * kpq) * CDIM + 4 * cg;
    st.q0 = *(const f32x4*)gq;
    st.q1 = *(const f32x4*)(gq + CDIM);
    #pragma unroll
    for (int i = 0; i < 4; ++i) {
      const int d = k0 + 2 * (kpk + 8 * i);
      const float* gk = kbase + (size_t)d * TDIM + t0 + 4 * tg;
      st.ka[i] = *(const f32x4*)gk;
      st.kb[i] = *(const f32x4*)(gk + TDIM);
    }
  };
  auto write_stage = [&](int b) {
    unsigned int* Au = (unsigned int*)Asbuf[b];
    unsigned int* Bu = (unsigned int*)Bsbuf[b];
    #pragma unroll
    for (int j = 0; j < 4; ++j)
      Au[(4 * cg + j) * (AS_STRIDE / 2) + kpq] = pk2(st.q0[j], st.q1[j]);
    #pragma unroll
    for (int i = 0; i < 4; ++i)
      #pragma unroll
      for (int j = 0; j < 4; ++j)
        Bu[(4 * tg + j) * (BS_STRIDE / 2) + kpk + 8 * i] = pk2(st.ka[i][j], st.kb[i][j]);
  };

  // prologue: tile 0 into buf0, tile 1 staged in regs
  issue_stage(0);
  write_stage(0);
  issue_stage(1);

  const int arow  = (32 * ct + l31) * AS_STRIDE;
  const int brow0 = (64 * ttp + l31) * BS_STRIDE;
  const int brow1 = brow0 + 32 * BS_STRIDE;

  for (int tb = 0; tb < 4; ++tb) {
    const int t0 = tb * TBLK;
    f32x16 sa[2];
    #pragma unroll
    for (int q = 0; q < 2; ++q)
      #pragma unroll
      for (int i = 0; i < 16; ++i) sa[q][i] = 0.0f;

    // ---- phase 1: S(64x256) += Q^T K, dbuf, 1 barrier per kit ----
    #pragma unroll
    for (int kit = 0; kit < 8; ++kit) {
      const int g = tb * 8 + kit;
      LGKM_BARRIER();                 // orders prev reads & writes vs this iter
      write_stage((kit + 1) & 1);     // tile g+1 -> other buffer
      {
        int gg = g + 2; if (gg > 31) gg = 31;
        issue_stage(gg);              // stays in flight across barriers
      }
      const unsigned short* Ab = Asbuf[kit & 1];
      const unsigned short* Bb = Bsbuf[kit & 1];
      #pragma unroll
      for (int ks = 0; ks < 4; ++ks) {
        const int koff = ks * 16 + 8 * lhi;
        s16x4 a0 = *(const s16x4*)&Ab[arow + koff];
        s16x4 a1 = *(const s16x4*)&Ab[arow + koff + 4];
        s16x8 av = __builtin_shufflevector(a0, a1, 0, 1, 2, 3, 4, 5, 6, 7);
        s16x4 b00 = *(const s16x4*)&Bb[brow0 + koff];
        s16x4 b01 = *(const s16x4*)&Bb[brow0 + koff + 4];
        s16x8 bv0 = __builtin_shufflevector(b00, b01, 0, 1, 2, 3, 4, 5, 6, 7);
        s16x4 b10 = *(const s16x4*)&Bb[brow1 + koff];
        s16x4 b11 = *(const s16x4*)&Bb[brow1 + koff + 4];
        s16x8 bv1 = __builtin_shufflevector(b10, b11, 0, 1, 2, 3, 4, 5, 6, 7);
        sa[0] = __builtin_amdgcn_mfma_f32_32x32x16_bf16(av, bv0, sa[0], 0, 0, 0);
        sa[1] = __builtin_amdgcn_mfma_f32_32x32x16_bf16(av, bv1, sa[1], 0, 0, 0);
      }
    }

    // ---- phase 2: p = mask * exp(s*scale); accumulate Z in regs ----
    #pragma unroll
    for (int tt2 = 0; tt2 < 2; ++tt2) {
      const int tcol = 64 * ttp + 32 * tt2 + l31;        // 0..255
      const float pm = ((tcol & 127) < vw) ? 1.0f : 0.0f;
      #pragma unroll
      for (int rg = 0; rg < 16; ++rg) {
        const int c_loc = 32 * ct + (rg & 3) + 8 * (rg >> 2) + 4 * lhi;
        float p = pm * __expf(sa[tt2][rg] * SCALE);
        Ps[c_loc * PS_STRIDE + tcol] = f2bf(p);
        z_loc[rg] += p;
      }
    }
    LGKM_BARRIER();  // Ps complete

    // ---- phase 3: O += P * V^T ; V direct from global, dist-2 prefetch ----
    {
      const float* vrow = vbase + (size_t)(64 * wave + l31) * TDIM + t0;
      VRegs vb[2];
      issue_v(vb[0], vrow, 0, lhi);
      issue_v(vb[1], vrow, 1, lhi);
      #pragma unroll
      for (int ks = 0; ks < 16; ++ks) {
        const int kk = ks * 16 + 8 * lhi;
        s16x8 pa[2];
        #pragma unroll
        for (int ci = 0; ci < 2; ++ci) {
          const int row = (32 * ci + l31) * PS_STRIDE;
          s16x4 x0 = *(const s16x4*)&Ps[row + kk];
          s16x4 x1 = *(const s16x4*)&Ps[row + kk + 4];
          pa[ci] = __builtin_shufflevector(x0, x1, 0, 1, 2, 3, 4, 5, 6, 7);
        }
        VRegs& vr = vb[ks & 1];
        s16x8 bv0 = cvt_bv(vr.a0, vr.a1);
        s16x8 bv1 = cvt_bv(vr.b0, vr.b1);
        if (ks < 14) issue_v(vr, vrow, ks + 2, lhi);
        o_acc[0][0] = __builtin_amdgcn_mfma_f32_32x32x16_bf16(pa[0], bv0, o_acc[0][0], 0, 0, 0);
        o_acc[1][0] = __builtin_amdgcn_mfma_f32_32x32x16_bf16(pa[1], bv0, o_acc[1][0], 0, 0, 0);
        o_acc[0][1] = __builtin_amdgcn_mfma_f32_32x32x16_bf16(pa[0], bv1, o_acc[0][1], 0, 0, 0);
        o_acc[1][1] = __builtin_amdgcn_mfma_f32_32x32x16_bf16(pa[1], bv1, o_acc[1][1], 0, 0, 0);
      }
    }
  }

  // ---- Z reduction: shfl-xor within 32-lane halves, then per-wave slots ----
  #pragma unroll
  for (int m = 1; m <= 16; m <<= 1)
    #pragma unroll
    for (int rg = 0; rg < 16; ++rg)
      z_loc[rg] += __shfl_xor(z_loc[rg], m);
  if (l31 == 0) {
    #pragma unroll
    for (int rg = 0; rg < 16; ++rg) {
      const int row = 32 * ct + (rg & 3) + 8 * (rg >> 2) + 4 * lhi;
      Zpart[64 * ttp + row] = z_loc[rg];
    }
  }
  LGKM_BARRIER();
  if (tid < 64)
    invZ[tid] = 1.0f / (Zpart[tid] + Zpart[64 + tid] + Zpart[128 + tid] + Zpart[192 + tid]);
  LGKM_BARRIER();

  // ---- epilogue: normalize, transpose via LDS, coalesced store ----
  float* outn = out + (size_t)n * DDIM * CDIM + c0;
  for (int ch = 0; ch < 4; ++ch) {          // d-chunk of 128
    if ((wave >> 1) == ch) {
      const int s = wave & 1;
      #pragma unroll
      for (int ci = 0; ci < 2; ++ci)
        #pragma unroll
        for (int dt = 0; dt < 2; ++dt)
          #pragma unroll
          for (int rg = 0; rg < 16; ++rg) {
            const int c_loc = 32 * ci + (rg & 3) + 8 * (rg >> 2) + 4 * lhi;
            const int ddl = 64 * s + 32 * dt + l31;
            Obuf[c_loc * 129 + ddl] = o_acc[ci][dt][rg] * invZ[c_loc];
          }
    }
    LGKM_BARRIER();
    {
      const int c = tid & 63;
      const int db = tid >> 6;
      #pragma unroll
      for (int p = 0; p < 16; ++p) {
        const int ddl = db + 8 * p;
        outn[(size_t)(128 * ch + ddl) * CDIM + c] = Obuf[c * 129 + ddl];
      }
    }
    LGKM_BARRIER();
  }
}

extern "C" void kernel_launch(void* const* d_in, const int* in_sizes, int n_in,
                              void* d_out, int out_size, void* d_ws, size_t ws_size,
                              hipStream_t stream) {
  const float* query  = (const float*)d_in[0];
  const float* key    = (const float*)d_in[1];
  const float* value  = (const float*)d_in[2];
  const float* ratios = (const float*)d_in[3];
  float* out = (float*)d_out;
  (void)in_sizes; (void)n_in; (void)out_size; (void)d_ws; (void)ws_size;
  dim3 grid(CDIM / CB, NS);   // (8, 64)
  attn_fused_kernel<<<grid, 512, 0, stream>>>(query, key, value, ratios, out);
}